// Round 1
// baseline (8741.366 us; speedup 1.0000x reference)
//
#include <hip/hip_runtime.h>
#include <hip/hip_bf16.h>

typedef unsigned short u16;
typedef __attribute__((ext_vector_type(8))) short short8;
typedef __attribute__((ext_vector_type(4))) float f32x4;

// ---------- helpers ----------
__device__ __forceinline__ float bf2f(u16 x){
    union { unsigned u; float f; } c; c.u = ((unsigned)x) << 16; return c.f;
}
__device__ __forceinline__ u16 f2bf(float f){
    union { float f; unsigned u; } c; c.f = f;
    unsigned u = c.u;
    return (u16)((u + 0x7FFFu + ((u >> 16) & 1u)) >> 16);
}
__device__ __forceinline__ f32x4 MFMA(short8 a, short8 b, f32x4 c){
    return __builtin_amdgcn_mfma_f32_16x16x32_bf16(a, b, c, 0, 0, 0);
}
__device__ __forceinline__ void gld_lds16(const u16* g, u16* l){
    __builtin_amdgcn_global_load_lds((const __attribute__((address_space(1))) unsigned int*)g,
                                     (__attribute__((address_space(3))) unsigned int*)l, 16, 0, 0);
}

#define SEQ 4096
#define HID 768
#define QKVW 2304

// ---------- generic GEMM: out = A[M,K] @ Bt[N,K]^T ----------
// 128x128 tile, BK=32, 4 waves (2x2).
// 2-phase double-buffered pipeline (T3-minimum): issue next-tile global_load_lds
// BEFORE current-tile ds_read+MFMA; single __syncthreads per k-step (its
// vmcnt(0) drain is the prefetch fence).
// OUT_MODE 0: bf16 store, +bias (f32), optional gelu.
// OUT_MODE 1: f32 atomicAdd partials (split-K via blockIdx.z, chunk size Kc).
template<int OUT_MODE, int ACT_GELU>
__global__ __launch_bounds__(256)
void gemm_bt(const u16* __restrict__ A, const u16* __restrict__ Bt,
             const float* __restrict__ bias, void* __restrict__ outp,
             int M, int N, int K, int Kc)
{
    __shared__ __align__(16) u16 As[2][128*32];
    __shared__ __align__(16) u16 Bs[2][128*32];
    const int tid  = threadIdx.x;
    const int w    = tid >> 6, lane = tid & 63;
    const int quad = lane >> 4, l16 = lane & 15;
    const int m0 = blockIdx.x * 128, n0 = blockIdx.y * 128;
    const int wm = (w >> 1) * 64, wn = (w & 1) * 64;
    const int kz0 = blockIdx.z * Kc;

    f32x4 acc[4][4];
    for (int i = 0; i < 4; i++) for (int j = 0; j < 4; j++)
        acc[i][j] = (f32x4){0.f, 0.f, 0.f, 0.f};

    // chunk c (0..511): 16 bytes = row (c>>2) of the 128-row tile, k-part (c&3)*8.
    const int c0 = tid, c1 = tid + 256;
    const int la0 = (w*64)*8;          // wave-uniform LDS offsets (lane*16B by HW)
    const int la1 = ((w+4)*64)*8;
    const u16* gA0 = A  + (size_t)(m0 + (c0>>2)) * K + (c0&3)*8 + kz0;
    const u16* gA1 = A  + (size_t)(m0 + (c1>>2)) * K + (c1&3)*8 + kz0;
    const u16* gB0 = Bt + (size_t)(n0 + (c0>>2)) * K + (c0&3)*8 + kz0;
    const u16* gB1 = Bt + (size_t)(n0 + (c1>>2)) * K + (c1&3)*8 + kz0;

    auto stage = [&](int buf, int k0) {
        gld_lds16(gA0 + k0, &As[buf][la0]);
        gld_lds16(gA1 + k0, &As[buf][la1]);
        gld_lds16(gB0 + k0, &Bs[buf][la0]);
        gld_lds16(gB1 + k0, &Bs[buf][la1]);
    };

    const int nk = Kc >> 5;
    stage(0, 0);
    __syncthreads();                       // drain prologue stage
    int cur = 0;
    for (int t = 0; t < nk; ++t) {
        if (t + 1 < nk) stage(cur ^ 1, (t + 1) * 32);   // prefetch next tile
        short8 af[4], bfr[4];
        for (int mt = 0; mt < 4; mt++)
            af[mt]  = *(const short8*)&As[cur][(wm + mt*16 + l16)*32 + quad*8];
        for (int nt = 0; nt < 4; nt++)
            bfr[nt] = *(const short8*)&Bs[cur][(wn + nt*16 + l16)*32 + quad*8];
        for (int mt = 0; mt < 4; mt++)
            for (int nt = 0; nt < 4; nt++)
                acc[mt][nt] = MFMA(af[mt], bfr[nt], acc[mt][nt]);
        __syncthreads();                   // vmcnt(0)+lgkm drain: prefetch landed,
        cur ^= 1;                          // all waves done reading As[cur]
    }

    if (OUT_MODE == 0) {
        u16* out = (u16*)outp;
        for (int mt = 0; mt < 4; mt++) {
            const int rbase = m0 + wm + mt*16 + quad*4;
            for (int nt = 0; nt < 4; nt++) {
                const int col = n0 + wn + nt*16 + l16;
                const float bc = bias ? bias[col] : 0.f;
                f32x4 v = acc[mt][nt];
                for (int reg = 0; reg < 4; reg++) {
                    const size_t idx = (size_t)(rbase + reg) * N + col;
                    float x = v[reg] + bc;
                    if (ACT_GELU) x = 0.5f * x * (1.f + erff(x * 0.7071067811865476f));
                    out[idx] = f2bf(x);
                }
            }
        }
    } else {
        float* out = (float*)outp;
        for (int mt = 0; mt < 4; mt++) {
            const int rbase = m0 + wm + mt*16 + quad*4;
            for (int nt = 0; nt < 4; nt++) {
                const int col = n0 + wn + nt*16 + l16;
                f32x4 v = acc[mt][nt];
                for (int reg = 0; reg < 4; reg++)
                    atomicAdd(&out[(size_t)(rbase + reg) * N + col], v[reg]);
            }
        }
    }
}

// ---------- per-layer weight prep: all 6 transposes + bias concat in ONE dispatch ----------
__global__ __launch_bounds__(256)
void prep_layer(const float* __restrict__ Wq, const float* __restrict__ Wk,
                const float* __restrict__ Wv, const float* __restrict__ Wo,
                const float* __restrict__ Wi, const float* __restrict__ Wo2,
                const float* __restrict__ bq, const float* __restrict__ bk,
                const float* __restrict__ bv,
                u16* __restrict__ WtQKV, u16* __restrict__ WtO,
                u16* __restrict__ WtI, u16* __restrict__ WtO2,
                float* __restrict__ bqkv)
{
    const int id  = blockIdx.x;
    const int tid = threadIdx.x;
    if (id == 6912) {                      // bias concat (q scaled by 1/8)
        for (int i = tid; i < QKVW; i += 256) {
            if (i < 768)       bqkv[i] = bq[i] * 0.125f;
            else if (i < 1536) bqkv[i] = bk[i - 768];
            else               bqkv[i] = bv[i - 1536];
        }
        return;
    }
    const float* src; u16* dst; int K, N, t; float scale = 1.f;
    if (id < 2304) {
        const int m = id / 576; t = id % 576; K = 768; N = 768;
        if      (m == 0) { src = Wq; dst = WtQKV;             scale = 0.125f; }
        else if (m == 1) { src = Wk; dst = WtQKV + 768*768; }
        else if (m == 2) { src = Wv; dst = WtQKV + 2*768*768; }
        else             { src = Wo; dst = WtO; }
    } else if (id < 4608) { t = id - 2304; K = 768;  N = 3072; src = Wi;  dst = WtI;  }
    else                  { t = id - 4608; K = 3072; N = 768;  src = Wo2; dst = WtO2; }

    const int ntx = N / 32;
    const int bx = (t / ntx) * 32, by = (t % ntx) * 32;
    __shared__ float tt[32][33];
    const int tx = tid & 31, ty = tid >> 5;
    for (int i = 0; i < 4; i++)
        tt[ty + i*8][tx] = src[(size_t)(bx + ty + i*8) * N + by + tx];
    __syncthreads();
    for (int i = 0; i < 4; i++)
        dst[(size_t)(by + ty + i*8) * K + bx + tx] = f2bf(tt[tx][ty + i*8] * scale);
}

// ---------- embedding ----------
__global__ void embed_kernel(const int* __restrict__ ids, const float* __restrict__ we,
                             const float* __restrict__ pe, const float* __restrict__ te,
                             u16* __restrict__ pb)
{
    const int t = blockIdx.x;
    const int s = t & (SEQ - 1);
    const int id = ids[t];
    const size_t wb = (size_t)id * HID;
    const size_t pbase = (size_t)(s + 2) * HID;
    for (int d = threadIdx.x; d < HID; d += 256)
        pb[(size_t)t * HID + d] = f2bf(we[wb + d] + pe[pbase + d] + te[d]);
}

// ---------- fused layernorm (bf16 pre): x = resid(f32, may be null) + pre ----------
__global__ __launch_bounds__(256)
void ln_kernel(const u16* __restrict__ pre, const float* __restrict__ resid,
               const float* __restrict__ g, const float* __restrict__ bta,
               float* __restrict__ h, u16* __restrict__ hb)
{
    const int t = blockIdx.x;
    float v[3], s = 0.f, s2 = 0.f;
    for (int i = 0; i < 3; i++) {
        const int d = threadIdx.x + i*256;
        float x = bf2f(pre[(size_t)t*HID + d]);
        if (resid) x += resid[(size_t)t*HID + d];
        v[i] = x; s += x; s2 += x*x;
    }
    for (int o = 32; o > 0; o >>= 1) { s += __shfl_xor(s, o, 64); s2 += __shfl_xor(s2, o, 64); }
    __shared__ float red[8];
    const int w = threadIdx.x >> 6, lane = threadIdx.x & 63;
    if (lane == 0) { red[w] = s; red[w+4] = s2; }
    __syncthreads();
    s  = red[0] + red[1] + red[2] + red[3];
    s2 = red[4] + red[5] + red[6] + red[7];
    const float mean = s * (1.f/768.f);
    const float var  = s2 * (1.f/768.f) - mean*mean;
    const float rs   = rsqrtf(fmaxf(var, 0.f) + 1e-5f);
    for (int i = 0; i < 3; i++) {
        const int d = threadIdx.x + i*256;
        const float y = (v[i] - mean) * rs * g[d] + bta[d];
        h [(size_t)t*HID + d] = y;
        hb[(size_t)t*HID + d] = f2bf(y);
    }
}

// ---------- fused layernorm (f32 pre from split-K atomics): x = pre + bias + resid ----------
__global__ __launch_bounds__(256)
void ln_kernel_f32(const float* __restrict__ pre, const float* __restrict__ bias,
                   const float* __restrict__ resid,
                   const float* __restrict__ g, const float* __restrict__ bta,
                   float* __restrict__ h, u16* __restrict__ hb)
{
    const int t = blockIdx.x;
    float v[3], s = 0.f, s2 = 0.f;
    for (int i = 0; i < 3; i++) {
        const int d = threadIdx.x + i*256;
        float x = pre[(size_t)t*HID + d] + bias[d] + resid[(size_t)t*HID + d];
        v[i] = x; s += x; s2 += x*x;
    }
    for (int o = 32; o > 0; o >>= 1) { s += __shfl_xor(s, o, 64); s2 += __shfl_xor(s2, o, 64); }
    __shared__ float red[8];
    const int w = threadIdx.x >> 6, lane = threadIdx.x & 63;
    if (lane == 0) { red[w] = s; red[w+4] = s2; }
    __syncthreads();
    s  = red[0] + red[1] + red[2] + red[3];
    s2 = red[4] + red[5] + red[6] + red[7];
    const float mean = s * (1.f/768.f);
    const float var  = s2 * (1.f/768.f) - mean*mean;
    const float rs   = rsqrtf(fmaxf(var, 0.f) + 1e-5f);
    for (int i = 0; i < 3; i++) {
        const int d = threadIdx.x + i*256;
        const float y = (v[i] - mean) * rs * g[d] + bta[d];
        h [(size_t)t*HID + d] = y;
        hb[(size_t)t*HID + d] = f2bf(y);
    }
}

// ---------- sliding-window attention ----------
__global__ __launch_bounds__(256)
void attn_kernel(const u16* __restrict__ qkv, const int* __restrict__ amask,
                 u16* __restrict__ aout)
{
    const int bid = blockIdx.x;
    const int c  = bid & 15;
    const int hh = (bid >> 4) % 12;
    const int b  = bid / 192;
    const int tid = threadIdx.x;
    const int w = tid >> 6, lane = tid & 63;
    const int quad = lane >> 4, l16 = lane & 15;

    __shared__ __align__(16) u16 Vt[64 * 72];
    __shared__ __align__(16) u16 P[4 * 64 * 72];
    __shared__ int kmS[64];

    const u16* qbase = qkv + (size_t)(b * SEQ) * QKVW + hh * 64;

    short8 qa[4][2];
    const int qrow_base = c * 256 + w * 64;
    for (int mt = 0; mt < 4; mt++)
        for (int ks = 0; ks < 2; ks++) {
            const int t_q = qrow_base + mt*16 + l16;
            qa[mt][ks] = *(const short8*)(qbase + (size_t)t_q * QKVW + ks*32 + quad*8);
        }

    f32x4 oacc[4][5];
    for (int i = 0; i < 4; i++) for (int j = 0; j < 5; j++)
        oacc[i][j] = (f32x4){0.f, 0.f, 0.f, 0.f};
    short8 ones8;
    for (int j = 0; j < 8; j++) ones8[j] = 0x3F80;

    const int kglob0 = (c - 1) * 256;
    u16* Pw = P + w * (64 * 72);

    for (int ch = 0; ch < 12; ch++) {
        __syncthreads();
        {
            const int kl = tid & 63;
            const int dpart = tid >> 6;
            const int gk = kglob0 + ch*64 + kl;
            const bool gok = (gk >= 0 && gk < SEQ);
            for (int i = 0; i < 2; i++) {
                const int d0 = dpart*16 + i*8;
                short8 vv = {0,0,0,0,0,0,0,0};
                if (gok) vv = *(const short8*)(qkv + (size_t)(b*SEQ + gk)*QKVW + 1536 + hh*64 + d0);
                for (int j = 0; j < 8; j++) Vt[(d0 + j)*72 + kl] = (u16)vv[j];
            }
            if (tid < 64) kmS[kl] = gok ? amask[b*SEQ + gk] : 0;
        }
        __syncthreads();

        for (int nt = 0; nt < 4; nt++) {
            short8 kb0 = {0,0,0,0,0,0,0,0}, kb1 = {0,0,0,0,0,0,0,0};
            const int gk = kglob0 + ch*64 + nt*16 + l16;
            if (gk >= 0 && gk < SEQ) {
                const u16* kp = qkv + (size_t)(b*SEQ + gk)*QKVW + 768 + hh*64;
                kb0 = *(const short8*)(kp + quad*8);
                kb1 = *(const short8*)(kp + 32 + quad*8);
            }
            f32x4 sacc[4];
            for (int mt = 0; mt < 4; mt++) {
                sacc[mt] = (f32x4){0.f, 0.f, 0.f, 0.f};
                sacc[mt] = MFMA(qa[mt][0], kb0, sacc[mt]);
                sacc[mt] = MFMA(qa[mt][1], kb1, sacc[mt]);
            }
            const int tband = ch*64 + nt*16 + l16;
            const int km = kmS[nt*16 + l16];
            for (int mt = 0; mt < 4; mt++)
                for (int reg = 0; reg < 4; reg++) {
                    const int rloc = mt*16 + quad*4 + reg;
                    const int rq = w*64 + rloc;
                    const int dt = tband - rq;
                    float p = 0.f;
                    if (dt >= 0 && dt <= 512 && km) p = __expf(fminf(sacc[mt][reg], 30.f));
                    Pw[rloc*72 + nt*16 + l16] = f2bf(p);
                }
        }

        for (int ks = 0; ks < 2; ks++) {
            short8 vb[4];
            for (int nd = 0; nd < 4; nd++)
                vb[nd] = *(const short8*)&Vt[(nd*16 + l16)*72 + ks*32 + quad*8];
            for (int mt = 0; mt < 4; mt++) {
                short8 pa = *(const short8*)&Pw[(mt*16 + l16)*72 + ks*32 + quad*8];
                for (int nd = 0; nd < 4; nd++)
                    oacc[mt][nd] = MFMA(pa, vb[nd], oacc[mt][nd]);
                oacc[mt][4] = MFMA(pa, ones8, oacc[mt][4]);
            }
        }
    }

    u16* obase = aout + (size_t)(b * SEQ) * HID + hh * 64;
    for (int mt = 0; mt < 4; mt++)
        for (int reg = 0; reg < 4; reg++) {
            const int t_q = qrow_base + mt*16 + quad*4 + reg;
            const float l = oacc[mt][4][reg];
            const float rl = (l > 1e-30f) ? 1.f / l : 0.f;
            for (int nd = 0; nd < 4; nd++)
                obase[(size_t)t_q * HID + nd*16 + l16] = f2bf(oacc[mt][nd][reg] * rl);
        }
}

// ---------- classifier ----------
__global__ void cls1(const float* __restrict__ h, const float* __restrict__ w1,
                     const float* __restrict__ b1, float* __restrict__ x)
{
    const int j = blockIdx.x, b = blockIdx.y;
    const float* p = h + (size_t)(b * SEQ) * HID;
    float s = 0.f;
    for (int d = threadIdx.x; d < HID; d += 64) s += p[d] * w1[(size_t)d*512 + j];
    for (int o = 32; o > 0; o >>= 1) s += __shfl_xor(s, o, 64);
    if (threadIdx.x == 0) x[b*512 + j] = fmaxf(s + b1[j], 0.f);
}

__global__ void cls2(const float* __restrict__ x, const float* __restrict__ w2,
                     const float* __restrict__ b2, float* __restrict__ out)
{
    const int j = blockIdx.x, b = blockIdx.y;
    float s = 0.f;
    for (int d = threadIdx.x; d < 512; d += 64) s += x[b*512 + d] * w2[(size_t)d*43 + j];
    for (int o = 32; o > 0; o >>= 1) s += __shfl_xor(s, o, 64);
    if (threadIdx.x == 0) out[b*43 + j] = s + b2[j];
}

// ---------- host ----------
extern "C" void kernel_launch(void* const* d_in, const int* in_sizes, int n_in,
                              void* d_out, int out_size, void* d_ws, size_t ws_size,
                              hipStream_t stream)
{
    const int*   ids   = (const int*)d_in[0];
    const int*   amask = (const int*)d_in[1];
    const float* we  = (const float*)d_in[2];
    const float* pe  = (const float*)d_in[3];
    const float* te  = (const float*)d_in[4];
    const float* eg  = (const float*)d_in[5];
    const float* ebp = (const float*)d_in[6];
    const float* Wq_  = (const float*)d_in[7];
    const float* bq_  = (const float*)d_in[8];
    const float* Wk_  = (const float*)d_in[9];
    const float* bk_  = (const float*)d_in[10];
    const float* Wv_  = (const float*)d_in[11];
    const float* bv_  = (const float*)d_in[12];
    const float* Wo_  = (const float*)d_in[13];
    const float* bo_  = (const float*)d_in[14];
    const float* g1_  = (const float*)d_in[15];
    const float* b1_  = (const float*)d_in[16];
    const float* Wi_  = (const float*)d_in[17];
    const float* bi_  = (const float*)d_in[18];
    const float* Wo2_ = (const float*)d_in[19];
    const float* bo2_ = (const float*)d_in[20];
    const float* g2_  = (const float*)d_in[21];
    const float* b2_  = (const float*)d_in[22];
    const float* cw1  = (const float*)d_in[23];
    const float* cb1  = (const float*)d_in[24];
    const float* cw2  = (const float*)d_in[25];
    const float* cb2  = (const float*)d_in[26];

    char* wsb = (char*)d_ws;
    size_t off = 0;
    auto alloc = [&](size_t bytes) -> void* {
        void* p = wsb + off; off += (bytes + 255) & ~(size_t)255; return p;
    };
    float* h    = (float*)alloc((size_t)8192*768*4);          // residual (f32)
    u16*   hb   = (u16*)  alloc((size_t)8192*768*2);          // residual (bf16)
    u16*   pb   = (u16*)  alloc((size_t)8192*768*2);          // pre-LN scratch (bf16)
    float* pf   = (float*)alloc((size_t)8192*768*4);          // f32 split-K accumulator
    u16*   U    = (u16*)  alloc((size_t)8192*3072*2);         // qkv|ao union == fbuf
    u16*   qkv  = U;
    u16*   ao   = U + (size_t)8192*QKVW;
    u16*   fbuf = U;
    u16*   WtQKV= (u16*)  alloc((size_t)QKVW*768*2);
    float* bqkv = (float*)alloc((size_t)QKVW*4);
    u16*   WtO  = (u16*)  alloc((size_t)768*768*2);
    u16*   WtI  = (u16*)  alloc((size_t)3072*768*2);
    u16*   WtO2 = (u16*)  alloc((size_t)768*3072*2);
    float* clsx = (float*)alloc((size_t)2*512*4);

    const size_t pf_bytes = (size_t)8192*768*4;

    embed_kernel<<<8192, 256, 0, stream>>>(ids, we, pe, te, pb);
    ln_kernel<<<8192, 256, 0, stream>>>(pb, nullptr, eg, ebp, h, hb);

    for (int l = 0; l < 12; l++) {
        const size_t wHH = (size_t)l * 768 * 768;
        const size_t wHF = (size_t)l * 768 * 3072;
        prep_layer<<<6913, 256, 0, stream>>>(Wq_ + wHH, Wk_ + wHH, Wv_ + wHH, Wo_ + wHH,
                                             Wi_ + wHF, Wo2_ + wHF,
                                             bq_ + l*768, bk_ + l*768, bv_ + l*768,
                                             WtQKV, WtO, WtI, WtO2, bqkv);

        // fused QKV projection (q pre-scaled by 1/8)
        gemm_bt<0,0><<<dim3(64,18,1), 256, 0, stream>>>(hb, WtQKV, bqkv, qkv, 8192, QKVW, 768, 768);
        // sliding-window attention
        attn_kernel<<<384, 256, 0, stream>>>(qkv, amask, ao);
        // output projection: split-K=2 f32 atomics; bias folded into LN1
        hipMemsetAsync(pf, 0, pf_bytes, stream);
        gemm_bt<1,0><<<dim3(64,6,2), 256, 0, stream>>>(ao, WtO, nullptr, pf, 8192, 768, 768, 384);
        ln_kernel_f32<<<8192, 256, 0, stream>>>(pf, bo_ + l*768, h, g1_ + l*768, b1_ + l*768, h, hb);
        // FFN
        gemm_bt<0,1><<<dim3(64,24,1), 256, 0, stream>>>(hb, WtI, bi_ + l*3072, fbuf, 8192, 3072, 768, 768);
        // FFN2: split-K=4 f32 atomics; bias folded into LN2
        hipMemsetAsync(pf, 0, pf_bytes, stream);
        gemm_bt<1,0><<<dim3(64,6,4), 256, 0, stream>>>(fbuf, WtO2, nullptr, pf, 8192, 768, 3072, 768);
        ln_kernel_f32<<<8192, 256, 0, stream>>>(pf, bo2_ + l*768, h, g2_ + l*768, b2_ + l*768, h, hb);
    }

    cls1<<<dim3(512,2), 64, 0, stream>>>(h, cw1, cb1, clsx);
    cls2<<<dim3(43,2),  64, 0, stream>>>(clsx, cw2, cb2, (float*)d_out);
}

// Round 2
// 4383.715 us; speedup vs baseline: 1.9941x; 1.9941x over previous
//
#include <hip/hip_runtime.h>
#include <hip/hip_bf16.h>

typedef unsigned short u16;
typedef __attribute__((ext_vector_type(8))) short short8;
typedef __attribute__((ext_vector_type(4))) float f32x4;

// ---------- helpers ----------
__device__ __forceinline__ float bf2f(u16 x){
    union { unsigned u; float f; } c; c.u = ((unsigned)x) << 16; return c.f;
}
__device__ __forceinline__ u16 f2bf(float f){
    union { float f; unsigned u; } c; c.f = f;
    unsigned u = c.u;
    return (u16)((u + 0x7FFFu + ((u >> 16) & 1u)) >> 16);
}
__device__ __forceinline__ f32x4 MFMA(short8 a, short8 b, f32x4 c){
    return __builtin_amdgcn_mfma_f32_16x16x32_bf16(a, b, c, 0, 0, 0);
}
__device__ __forceinline__ void gld_lds16(const u16* g, u16* l){
    __builtin_amdgcn_global_load_lds((const __attribute__((address_space(1))) unsigned int*)g,
                                     (__attribute__((address_space(3))) unsigned int*)l, 16, 0, 0);
}

#define SEQ 4096
#define HID 768
#define QKVW 2304

// ---------- generic GEMM: out = A[M,K] @ Bt[N,K]^T ----------
// 128x128 tile, BK=32, 4 waves (2x2).
// Depth-2 pipeline (T3+T4): triple-buffered LDS, 2 stages in flight,
// counted s_waitcnt vmcnt(4) + raw s_barrier once per k-step.
//   iter t: wait stage(t) [vmcnt(4): stage(t+1) stays airborne] -> barrier
//           -> issue stage(t+2) -> ds_read buf[t%3] -> MFMA.
// Race check: buf[t%3] is next overwritten by stage(t+3), issued after the
// iter-(t+1) barrier, which every wave reaches only after finishing its
// iter-t reads. Cross-wave visibility: each wave drains its OWN vmcnt
// before the barrier, so after the barrier all waves' stage(t) landed.
// OUT_MODE 0: bf16 store, +bias (f32), optional gelu.
// OUT_MODE 1: f32 partial store to outp + blockIdx.z*M*N (split-K, no atomics).
template<int OUT_MODE, int ACT_GELU>
__global__ __launch_bounds__(256)
void gemm_bt(const u16* __restrict__ A, const u16* __restrict__ Bt,
             const float* __restrict__ bias, void* __restrict__ outp,
             int M, int N, int K, int Kc)
{
    __shared__ __align__(16) u16 As[3][128*32];
    __shared__ __align__(16) u16 Bs[3][128*32];
    const int tid  = threadIdx.x;
    const int w    = tid >> 6, lane = tid & 63;
    const int quad = lane >> 4, l16 = lane & 15;
    const int m0 = blockIdx.x * 128, n0 = blockIdx.y * 128;
    const int wm = (w >> 1) * 64, wn = (w & 1) * 64;
    const int kz0 = blockIdx.z * Kc;

    f32x4 acc[4][4];
    for (int i = 0; i < 4; i++) for (int j = 0; j < 4; j++)
        acc[i][j] = (f32x4){0.f, 0.f, 0.f, 0.f};

    // chunk c (0..511): 16 bytes = row (c>>2) of the 128-row tile, k-part (c&3)*8.
    const int c0 = tid, c1 = tid + 256;
    const int la0 = (w*64)*8;          // wave-uniform LDS offsets (lane*16B by HW)
    const int la1 = ((w+4)*64)*8;
    const u16* gA0 = A  + (size_t)(m0 + (c0>>2)) * K + (c0&3)*8 + kz0;
    const u16* gA1 = A  + (size_t)(m0 + (c1>>2)) * K + (c1&3)*8 + kz0;
    const u16* gB0 = Bt + (size_t)(n0 + (c0>>2)) * K + (c0&3)*8 + kz0;
    const u16* gB1 = Bt + (size_t)(n0 + (c1>>2)) * K + (c1&3)*8 + kz0;

    auto stage = [&](int buf, int k0) {
        gld_lds16(gA0 + k0, &As[buf][la0]);
        gld_lds16(gA1 + k0, &As[buf][la1]);
        gld_lds16(gB0 + k0, &Bs[buf][la0]);
        gld_lds16(gB1 + k0, &Bs[buf][la1]);
    };

    const int nk = Kc >> 5;            // >= 12 for all call sites
    stage(0, 0);
    stage(1, 32);
    for (int t = 0; t < nk; ++t) {
        if (t + 1 < nk) { asm volatile("s_waitcnt vmcnt(4)" ::: "memory"); }
        else            { asm volatile("s_waitcnt vmcnt(0)" ::: "memory"); }
        __builtin_amdgcn_s_barrier();
        if (t + 2 < nk) stage((t + 2) % 3, (t + 2) * 32);
        const int cur = t % 3;
        short8 af[4], bfr[4];
        for (int mt = 0; mt < 4; mt++)
            af[mt]  = *(const short8*)&As[cur][(wm + mt*16 + l16)*32 + quad*8];
        for (int nt = 0; nt < 4; nt++)
            bfr[nt] = *(const short8*)&Bs[cur][(wn + nt*16 + l16)*32 + quad*8];
        __builtin_amdgcn_s_setprio(1);
        for (int mt = 0; mt < 4; mt++)
            for (int nt = 0; nt < 4; nt++)
                acc[mt][nt] = MFMA(af[mt], bfr[nt], acc[mt][nt]);
        __builtin_amdgcn_s_setprio(0);
    }

    if (OUT_MODE == 0) {
        u16* out = (u16*)outp;
        for (int mt = 0; mt < 4; mt++) {
            const int rbase = m0 + wm + mt*16 + quad*4;
            for (int nt = 0; nt < 4; nt++) {
                const int col = n0 + wn + nt*16 + l16;
                const float bc = bias ? bias[col] : 0.f;
                f32x4 v = acc[mt][nt];
                for (int reg = 0; reg < 4; reg++) {
                    const size_t idx = (size_t)(rbase + reg) * N + col;
                    float x = v[reg] + bc;
                    if (ACT_GELU) x = 0.5f * x * (1.f + erff(x * 0.7071067811865476f));
                    out[idx] = f2bf(x);
                }
            }
        }
    } else {
        float* out = (float*)outp + (size_t)blockIdx.z * M * N;
        for (int mt = 0; mt < 4; mt++) {
            const int rbase = m0 + wm + mt*16 + quad*4;
            for (int nt = 0; nt < 4; nt++) {
                const int col = n0 + wn + nt*16 + l16;
                f32x4 v = acc[mt][nt];
                for (int reg = 0; reg < 4; reg++)
                    out[(size_t)(rbase + reg) * N + col] = v[reg];
            }
        }
    }
}

// ---------- per-layer weight prep: all 6 transposes + bias concat in ONE dispatch ----------
__global__ __launch_bounds__(256)
void prep_layer(const float* __restrict__ Wq, const float* __restrict__ Wk,
                const float* __restrict__ Wv, const float* __restrict__ Wo,
                const float* __restrict__ Wi, const float* __restrict__ Wo2,
                const float* __restrict__ bq, const float* __restrict__ bk,
                const float* __restrict__ bv,
                u16* __restrict__ WtQKV, u16* __restrict__ WtO,
                u16* __restrict__ WtI, u16* __restrict__ WtO2,
                float* __restrict__ bqkv)
{
    const int id  = blockIdx.x;
    const int tid = threadIdx.x;
    if (id == 6912) {                      // bias concat (q scaled by 1/8)
        for (int i = tid; i < QKVW; i += 256) {
            if (i < 768)       bqkv[i] = bq[i] * 0.125f;
            else if (i < 1536) bqkv[i] = bk[i - 768];
            else               bqkv[i] = bv[i - 1536];
        }
        return;
    }
    const float* src; u16* dst; int K, N, t; float scale = 1.f;
    if (id < 2304) {
        const int m = id / 576; t = id % 576; K = 768; N = 768;
        if      (m == 0) { src = Wq; dst = WtQKV;             scale = 0.125f; }
        else if (m == 1) { src = Wk; dst = WtQKV + 768*768; }
        else if (m == 2) { src = Wv; dst = WtQKV + 2*768*768; }
        else             { src = Wo; dst = WtO; }
    } else if (id < 4608) { t = id - 2304; K = 768;  N = 3072; src = Wi;  dst = WtI;  }
    else                  { t = id - 4608; K = 3072; N = 768;  src = Wo2; dst = WtO2; }

    const int ntx = N / 32;
    const int bx = (t / ntx) * 32, by = (t % ntx) * 32;
    __shared__ float tt[32][33];
    const int tx = tid & 31, ty = tid >> 5;
    for (int i = 0; i < 4; i++)
        tt[ty + i*8][tx] = src[(size_t)(bx + ty + i*8) * N + by + tx];
    __syncthreads();
    for (int i = 0; i < 4; i++)
        dst[(size_t)(by + ty + i*8) * K + bx + tx] = f2bf(tt[tx][ty + i*8] * scale);
}

// ---------- embedding ----------
__global__ void embed_kernel(const int* __restrict__ ids, const float* __restrict__ we,
                             const float* __restrict__ pe, const float* __restrict__ te,
                             u16* __restrict__ pb)
{
    const int t = blockIdx.x;
    const int s = t & (SEQ - 1);
    const int id = ids[t];
    const size_t wb = (size_t)id * HID;
    const size_t pbase = (size_t)(s + 2) * HID;
    for (int d = threadIdx.x; d < HID; d += 256)
        pb[(size_t)t * HID + d] = f2bf(we[wb + d] + pe[pbase + d] + te[d]);
}

// ---------- fused layernorm (bf16 pre): x = resid(f32, may be null) + pre ----------
__global__ __launch_bounds__(256)
void ln_kernel(const u16* __restrict__ pre, const float* __restrict__ resid,
               const float* __restrict__ g, const float* __restrict__ bta,
               float* __restrict__ h, u16* __restrict__ hb)
{
    const int t = blockIdx.x;
    float v[3], s = 0.f, s2 = 0.f;
    for (int i = 0; i < 3; i++) {
        const int d = threadIdx.x + i*256;
        float x = bf2f(pre[(size_t)t*HID + d]);
        if (resid) x += resid[(size_t)t*HID + d];
        v[i] = x; s += x; s2 += x*x;
    }
    for (int o = 32; o > 0; o >>= 1) { s += __shfl_xor(s, o, 64); s2 += __shfl_xor(s2, o, 64); }
    __shared__ float red[8];
    const int w = threadIdx.x >> 6, lane = threadIdx.x & 63;
    if (lane == 0) { red[w] = s; red[w+4] = s2; }
    __syncthreads();
    s  = red[0] + red[1] + red[2] + red[3];
    s2 = red[4] + red[5] + red[6] + red[7];
    const float mean = s * (1.f/768.f);
    const float var  = s2 * (1.f/768.f) - mean*mean;
    const float rs   = rsqrtf(fmaxf(var, 0.f) + 1e-5f);
    for (int i = 0; i < 3; i++) {
        const int d = threadIdx.x + i*256;
        const float y = (v[i] - mean) * rs * g[d] + bta[d];
        h [(size_t)t*HID + d] = y;
        hb[(size_t)t*HID + d] = f2bf(y);
    }
}

// ---------- fused layernorm (two f32 split-K partials): x = p0 + p1 + bias + resid ----------
__global__ __launch_bounds__(256)
void ln_kernel_f32(const float* __restrict__ p0, const float* __restrict__ p1,
                   const float* __restrict__ bias, const float* __restrict__ resid,
                   const float* __restrict__ g, const float* __restrict__ bta,
                   float* __restrict__ h, u16* __restrict__ hb)
{
    const int t = blockIdx.x;
    float v[3], s = 0.f, s2 = 0.f;
    for (int i = 0; i < 3; i++) {
        const int d = threadIdx.x + i*256;
        const size_t ix = (size_t)t*HID + d;
        float x = p0[ix] + p1[ix] + bias[d] + resid[ix];
        v[i] = x; s += x; s2 += x*x;
    }
    for (int o = 32; o > 0; o >>= 1) { s += __shfl_xor(s, o, 64); s2 += __shfl_xor(s2, o, 64); }
    __shared__ float red[8];
    const int w = threadIdx.x >> 6, lane = threadIdx.x & 63;
    if (lane == 0) { red[w] = s; red[w+4] = s2; }
    __syncthreads();
    s  = red[0] + red[1] + red[2] + red[3];
    s2 = red[4] + red[5] + red[6] + red[7];
    const float mean = s * (1.f/768.f);
    const float var  = s2 * (1.f/768.f) - mean*mean;
    const float rs   = rsqrtf(fmaxf(var, 0.f) + 1e-5f);
    for (int i = 0; i < 3; i++) {
        const int d = threadIdx.x + i*256;
        const float y = (v[i] - mean) * rs * g[d] + bta[d];
        h [(size_t)t*HID + d] = y;
        hb[(size_t)t*HID + d] = f2bf(y);
    }
}

// ---------- sliding-window attention ----------
__global__ __launch_bounds__(256)
void attn_kernel(const u16* __restrict__ qkv, const int* __restrict__ amask,
                 u16* __restrict__ aout)
{
    const int bid = blockIdx.x;
    const int c  = bid & 15;
    const int hh = (bid >> 4) % 12;
    const int b  = bid / 192;
    const int tid = threadIdx.x;
    const int w = tid >> 6, lane = tid & 63;
    const int quad = lane >> 4, l16 = lane & 15;

    __shared__ __align__(16) u16 Vt[64 * 72];
    __shared__ __align__(16) u16 P[4 * 64 * 72];
    __shared__ int kmS[64];

    const u16* qbase = qkv + (size_t)(b * SEQ) * QKVW + hh * 64;

    short8 qa[4][2];
    const int qrow_base = c * 256 + w * 64;
    for (int mt = 0; mt < 4; mt++)
        for (int ks = 0; ks < 2; ks++) {
            const int t_q = qrow_base + mt*16 + l16;
            qa[mt][ks] = *(const short8*)(qbase + (size_t)t_q * QKVW + ks*32 + quad*8);
        }

    f32x4 oacc[4][5];
    for (int i = 0; i < 4; i++) for (int j = 0; j < 5; j++)
        oacc[i][j] = (f32x4){0.f, 0.f, 0.f, 0.f};
    short8 ones8;
    for (int j = 0; j < 8; j++) ones8[j] = 0x3F80;

    const int kglob0 = (c - 1) * 256;
    u16* Pw = P + w * (64 * 72);

    for (int ch = 0; ch < 12; ch++) {
        __syncthreads();
        {
            const int kl = tid & 63;
            const int dpart = tid >> 6;
            const int gk = kglob0 + ch*64 + kl;
            const bool gok = (gk >= 0 && gk < SEQ);
            for (int i = 0; i < 2; i++) {
                const int d0 = dpart*16 + i*8;
                short8 vv = {0,0,0,0,0,0,0,0};
                if (gok) vv = *(const short8*)(qkv + (size_t)(b*SEQ + gk)*QKVW + 1536 + hh*64 + d0);
                for (int j = 0; j < 8; j++) Vt[(d0 + j)*72 + kl] = (u16)vv[j];
            }
            if (tid < 64) kmS[kl] = gok ? amask[b*SEQ + gk] : 0;
        }
        __syncthreads();

        for (int nt = 0; nt < 4; nt++) {
            short8 kb0 = {0,0,0,0,0,0,0,0}, kb1 = {0,0,0,0,0,0,0,0};
            const int gk = kglob0 + ch*64 + nt*16 + l16;
            if (gk >= 0 && gk < SEQ) {
                const u16* kp = qkv + (size_t)(b*SEQ + gk)*QKVW + 768 + hh*64;
                kb0 = *(const short8*)(kp + quad*8);
                kb1 = *(const short8*)(kp + 32 + quad*8);
            }
            f32x4 sacc[4];
            for (int mt = 0; mt < 4; mt++) {
                sacc[mt] = (f32x4){0.f, 0.f, 0.f, 0.f};
                sacc[mt] = MFMA(qa[mt][0], kb0, sacc[mt]);
                sacc[mt] = MFMA(qa[mt][1], kb1, sacc[mt]);
            }
            const int tband = ch*64 + nt*16 + l16;
            const int km = kmS[nt*16 + l16];
            for (int mt = 0; mt < 4; mt++)
                for (int reg = 0; reg < 4; reg++) {
                    const int rloc = mt*16 + quad*4 + reg;
                    const int rq = w*64 + rloc;
                    const int dt = tband - rq;
                    float p = 0.f;
                    if (dt >= 0 && dt <= 512 && km) p = __expf(fminf(sacc[mt][reg], 30.f));
                    Pw[rloc*72 + nt*16 + l16] = f2bf(p);
                }
        }

        for (int ks = 0; ks < 2; ks++) {
            short8 vb[4];
            for (int nd = 0; nd < 4; nd++)
                vb[nd] = *(const short8*)&Vt[(nd*16 + l16)*72 + ks*32 + quad*8];
            for (int mt = 0; mt < 4; mt++) {
                short8 pa = *(const short8*)&Pw[(mt*16 + l16)*72 + ks*32 + quad*8];
                for (int nd = 0; nd < 4; nd++)
                    oacc[mt][nd] = MFMA(pa, vb[nd], oacc[mt][nd]);
                oacc[mt][4] = MFMA(pa, ones8, oacc[mt][4]);
            }
        }
    }

    u16* obase = aout + (size_t)(b * SEQ) * HID + hh * 64;
    for (int mt = 0; mt < 4; mt++)
        for (int reg = 0; reg < 4; reg++) {
            const int t_q = qrow_base + mt*16 + quad*4 + reg;
            const float l = oacc[mt][4][reg];
            const float rl = (l > 1e-30f) ? 1.f / l : 0.f;
            for (int nd = 0; nd < 4; nd++)
                obase[(size_t)t_q * HID + nd*16 + l16] = f2bf(oacc[mt][nd][reg] * rl);
        }
}

// ---------- classifier ----------
__global__ void cls1(const float* __restrict__ h, const float* __restrict__ w1,
                     const float* __restrict__ b1, float* __restrict__ x)
{
    const int j = blockIdx.x, b = blockIdx.y;
    const float* p = h + (size_t)(b * SEQ) * HID;
    float s = 0.f;
    for (int d = threadIdx.x; d < HID; d += 64) s += p[d] * w1[(size_t)d*512 + j];
    for (int o = 32; o > 0; o >>= 1) s += __shfl_xor(s, o, 64);
    if (threadIdx.x == 0) x[b*512 + j] = fmaxf(s + b1[j], 0.f);
}

__global__ void cls2(const float* __restrict__ x, const float* __restrict__ w2,
                     const float* __restrict__ b2, float* __restrict__ out)
{
    const int j = blockIdx.x, b = blockIdx.y;
    float s = 0.f;
    for (int d = threadIdx.x; d < 512; d += 64) s += x[b*512 + d] * w2[(size_t)d*43 + j];
    for (int o = 32; o > 0; o >>= 1) s += __shfl_xor(s, o, 64);
    if (threadIdx.x == 0) out[b*43 + j] = s + b2[j];
}

// ---------- host ----------
extern "C" void kernel_launch(void* const* d_in, const int* in_sizes, int n_in,
                              void* d_out, int out_size, void* d_ws, size_t ws_size,
                              hipStream_t stream)
{
    const int*   ids   = (const int*)d_in[0];
    const int*   amask = (const int*)d_in[1];
    const float* we  = (const float*)d_in[2];
    const float* pe  = (const float*)d_in[3];
    const float* te  = (const float*)d_in[4];
    const float* eg  = (const float*)d_in[5];
    const float* ebp = (const float*)d_in[6];
    const float* Wq_  = (const float*)d_in[7];
    const float* bq_  = (const float*)d_in[8];
    const float* Wk_  = (const float*)d_in[9];
    const float* bk_  = (const float*)d_in[10];
    const float* Wv_  = (const float*)d_in[11];
    const float* bv_  = (const float*)d_in[12];
    const float* Wo_  = (const float*)d_in[13];
    const float* bo_  = (const float*)d_in[14];
    const float* g1_  = (const float*)d_in[15];
    const float* b1_  = (const float*)d_in[16];
    const float* Wi_  = (const float*)d_in[17];
    const float* bi_  = (const float*)d_in[18];
    const float* Wo2_ = (const float*)d_in[19];
    const float* bo2_ = (const float*)d_in[20];
    const float* g2_  = (const float*)d_in[21];
    const float* b2_  = (const float*)d_in[22];
    const float* cw1  = (const float*)d_in[23];
    const float* cb1  = (const float*)d_in[24];
    const float* cw2  = (const float*)d_in[25];
    const float* cb2  = (const float*)d_in[26];

    char* wsb = (char*)d_ws;
    size_t off = 0;
    auto alloc = [&](size_t bytes) -> void* {
        void* p = wsb + off; off += (bytes + 255) & ~(size_t)255; return p;
    };
    const size_t MN = (size_t)8192 * 768;
    float* h    = (float*)alloc(MN*4);                        // residual (f32)
    u16*   hb   = (u16*)  alloc(MN*2);                        // residual (bf16)
    u16*   pb   = (u16*)  alloc(MN*2);                        // pre-LN scratch (bf16)
    float* pf   = (float*)alloc(MN*4*2);                      // 2x f32 split-K partials
    u16*   U    = (u16*)  alloc((size_t)8192*3072*2);         // qkv|ao union == fbuf
    u16*   qkv  = U;
    u16*   ao   = U + (size_t)8192*QKVW;
    u16*   fbuf = U;
    u16*   WtQKV= (u16*)  alloc((size_t)QKVW*768*2);
    float* bqkv = (float*)alloc((size_t)QKVW*4);
    u16*   WtO  = (u16*)  alloc((size_t)768*768*2);
    u16*   WtI  = (u16*)  alloc((size_t)3072*768*2);
    u16*   WtO2 = (u16*)  alloc((size_t)768*3072*2);
    float* clsx = (float*)alloc((size_t)2*512*4);

    embed_kernel<<<8192, 256, 0, stream>>>(ids, we, pe, te, pb);
    ln_kernel<<<8192, 256, 0, stream>>>(pb, nullptr, eg, ebp, h, hb);

    for (int l = 0; l < 12; l++) {
        const size_t wHH = (size_t)l * 768 * 768;
        const size_t wHF = (size_t)l * 768 * 3072;
        prep_layer<<<6913, 256, 0, stream>>>(Wq_ + wHH, Wk_ + wHH, Wv_ + wHH, Wo_ + wHH,
                                             Wi_ + wHF, Wo2_ + wHF,
                                             bq_ + l*768, bk_ + l*768, bv_ + l*768,
                                             WtQKV, WtO, WtI, WtO2, bqkv);

        // fused QKV projection (q pre-scaled by 1/8)
        gemm_bt<0,0><<<dim3(64,18,1), 256, 0, stream>>>(hb, WtQKV, bqkv, qkv, 8192, QKVW, 768, 768);
        // sliding-window attention
        attn_kernel<<<384, 256, 0, stream>>>(qkv, amask, ao);
        // output projection: split-K=2 into f32 partial buffers; bias folded into LN1
        gemm_bt<1,0><<<dim3(64,6,2), 256, 0, stream>>>(ao, WtO, nullptr, pf, 8192, 768, 768, 384);
        ln_kernel_f32<<<8192, 256, 0, stream>>>(pf, pf + MN, bo_ + l*768, h,
                                                g1_ + l*768, b1_ + l*768, h, hb);
        // FFN
        gemm_bt<0,1><<<dim3(64,24,1), 256, 0, stream>>>(hb, WtI, bi_ + l*3072, fbuf, 8192, 3072, 768, 768);
        // FFN2: split-K=2 into f32 partial buffers; bias folded into LN2
        gemm_bt<1,0><<<dim3(64,6,2), 256, 0, stream>>>(fbuf, WtO2, nullptr, pf, 8192, 768, 3072, 1536);
        ln_kernel_f32<<<8192, 256, 0, stream>>>(pf, pf + MN, bo2_ + l*768, h,
                                                g2_ + l*768, b2_ + l*768, h, hb);
    }

    cls1<<<dim3(512,2), 64, 0, stream>>>(h, cw1, cb1, clsx);
    cls2<<<dim3(43,2),  64, 0, stream>>>(clsx, cw2, cb2, (float*)d_out);
}

// Round 3
// 3939.426 us; speedup vs baseline: 2.2189x; 1.1128x over previous
//
#include <hip/hip_runtime.h>
#include <hip/hip_bf16.h>

typedef unsigned short u16;
typedef __attribute__((ext_vector_type(8))) short short8;
typedef __attribute__((ext_vector_type(4))) float f32x4;

// ---------- helpers ----------
__device__ __forceinline__ float bf2f(u16 x){
    union { unsigned u; float f; } c; c.u = ((unsigned)x) << 16; return c.f;
}
__device__ __forceinline__ u16 f2bf(float f){
    union { float f; unsigned u; } c; c.f = f;
    unsigned u = c.u;
    return (u16)((u + 0x7FFFu + ((u >> 16) & 1u)) >> 16);
}
__device__ __forceinline__ f32x4 MFMA(short8 a, short8 b, f32x4 c){
    return __builtin_amdgcn_mfma_f32_16x16x32_bf16(a, b, c, 0, 0, 0);
}
__device__ __forceinline__ void gld_lds16(const u16* g, u16* l){
    __builtin_amdgcn_global_load_lds((const __attribute__((address_space(1))) unsigned int*)g,
                                     (__attribute__((address_space(3))) unsigned int*)l, 16, 0, 0);
}

#define SEQ 4096
#define HID 768
#define QKVW 2304

// ---------- generic GEMM: out = A[M,K] @ Bt[N,K]^T ----------
// 128x128 tile, BK=32, 4 waves (2x2).
// Depth-2 pipeline (T3+T4): triple-buffered LDS, 2 stages in flight,
// counted s_waitcnt vmcnt(4) + raw s_barrier once per k-step.
// T2 (rule-21 both-sides): chunk c = (row r=c>>2, slot s=c&3) stages global
// k-part kp = s ^ ((r>>1)&3) (involution); ds_read uses slot quad^((l16>>1)&3)
// -> per-16-lane-group banks spread evenly (2/bank, free).
// T1: XCD swizzle, each XCD owns a contiguous 8-wide x-chunk (requires gridDim.x==64).
// OUT_MODE 0: bf16 store via LDS-coalesced epilogue (+bias, optional gelu).
// OUT_MODE 1: f32 partial store to outp + blockIdx.z*M*N (split-K, no atomics).
template<int OUT_MODE, int ACT_GELU>
__global__ __launch_bounds__(256)
void gemm_bt(const u16* __restrict__ A, const u16* __restrict__ Bt,
             const float* __restrict__ bias, void* __restrict__ outp,
             int M, int N, int K, int Kc)
{
    __shared__ __align__(16) u16 SM[6*4096];          // 48 KB: As[3][4096] | Bs[3][4096]
    const int tid  = threadIdx.x;
    const int w    = tid >> 6, lane = tid & 63;
    const int quad = lane >> 4, l16 = lane & 15;

    // XCD-aware remap: consecutive bids round-robin XCDs; give each XCD a
    // contiguous x-chunk (8 x-values) across all y -> A-slice stays L2-resident.
    const int bid = blockIdx.x + (gridDim.x * blockIdx.y);
    const int xcd = bid & 7, idx = bid >> 3;
    const int m0 = (xcd * 8 + (idx & 7)) * 128;
    const int n0 = (idx >> 3) * 128;

    const int wm = (w >> 1) * 64, wn = (w & 1) * 64;
    const int kz0 = blockIdx.z * Kc;

    f32x4 acc[4][4];
    for (int i = 0; i < 4; i++) for (int j = 0; j < 4; j++)
        acc[i][j] = (f32x4){0.f, 0.f, 0.f, 0.f};

    // staging chunks: c0 covers rows 0..63, c1 rows 64..127 of the tile.
    const int c0 = tid, c1 = tid + 256;
    const int r0 = c0 >> 2, kp0 = (c0 & 3) ^ ((r0 >> 1) & 3);
    const int r1 = c1 >> 2, kp1 = (c1 & 3) ^ ((r1 >> 1) & 3);
    const int la0 = (w*64)*8;          // wave-uniform LDS offsets (lane*16B by HW)
    const int la1 = ((w+4)*64)*8;
    const u16* gA0 = A  + (size_t)(m0 + r0) * K + kp0*8 + kz0;
    const u16* gA1 = A  + (size_t)(m0 + r1) * K + kp1*8 + kz0;
    const u16* gB0 = Bt + (size_t)(n0 + r0) * K + kp0*8 + kz0;
    const u16* gB1 = Bt + (size_t)(n0 + r1) * K + kp1*8 + kz0;

    auto stage = [&](int buf, int k0) {
        gld_lds16(gA0 + k0, SM + buf*4096 + la0);
        gld_lds16(gA1 + k0, SM + buf*4096 + la1);
        gld_lds16(gB0 + k0, SM + 12288 + buf*4096 + la0);
        gld_lds16(gB1 + k0, SM + 12288 + buf*4096 + la1);
    };

    const int sOff = (quad ^ ((l16 >> 1) & 3)) * 8;   // swizzled slot (u16 units)

    const int nk = Kc >> 5;            // >= 12 for all call sites
    stage(0, 0);
    stage(1, 32);
    for (int t = 0; t < nk; ++t) {
        if (t + 1 < nk) { asm volatile("s_waitcnt vmcnt(4)" ::: "memory"); }
        else            { asm volatile("s_waitcnt vmcnt(0)" ::: "memory"); }
        __builtin_amdgcn_s_barrier();
        if (t + 2 < nk) stage((t + 2) % 3, (t + 2) * 32);
        const int cur = t % 3;
        const u16* Ab = SM + cur*4096;
        const u16* Bb = SM + 12288 + cur*4096;
        short8 af[4], bfr[4];
        for (int mt = 0; mt < 4; mt++)
            af[mt]  = *(const short8*)&Ab[(wm + mt*16 + l16)*32 + sOff];
        for (int nt = 0; nt < 4; nt++)
            bfr[nt] = *(const short8*)&Bb[(wn + nt*16 + l16)*32 + sOff];
        __builtin_amdgcn_s_setprio(1);
        for (int mt = 0; mt < 4; mt++)
            for (int nt = 0; nt < 4; nt++)
                acc[mt][nt] = MFMA(af[mt], bfr[nt], acc[mt][nt]);
        __builtin_amdgcn_s_setprio(0);
    }

    if (OUT_MODE == 0) {
        // LDS-coalesced epilogue: stage C tile as bf16 [128][132] (stride 132
        // -> quad-rows 8 banks apart, conflict-free), then 16B coalesced stores.
        u16* out = (u16*)outp;
        __syncthreads();                       // done reading As/Bs
        u16* Cs = SM;                          // 128*132 u16 = 33 KB (fits 48 KB)
        const int CS = 132;
        for (int mt = 0; mt < 4; mt++) {
            const int rb = wm + mt*16 + quad*4;
            for (int nt = 0; nt < 4; nt++) {
                const int cl = wn + nt*16 + l16;
                const float bc = bias ? bias[n0 + cl] : 0.f;
                f32x4 v = acc[mt][nt];
                for (int reg = 0; reg < 4; reg++) {
                    float x = v[reg] + bc;
                    if (ACT_GELU) x = 0.5f * x * (1.f + erff(x * 0.7071067811865476f));
                    Cs[(rb + reg)*CS + cl] = f2bf(x);
                }
            }
        }
        __syncthreads();
        for (int i = 0; i < 8; i++) {
            const int slot = tid + i*256;      // 0..2047
            const int row = slot >> 4, seg = slot & 15;
            short8 val = *(const short8*)&Cs[row*CS + seg*8];
            *(short8*)&out[(size_t)(m0 + row) * N + n0 + seg*8] = val;
        }
    } else {
        float* out = (float*)outp + (size_t)blockIdx.z * M * N;
        for (int mt = 0; mt < 4; mt++) {
            const int rbase = m0 + wm + mt*16 + quad*4;
            for (int nt = 0; nt < 4; nt++) {
                const int col = n0 + wn + nt*16 + l16;
                f32x4 v = acc[mt][nt];
                for (int reg = 0; reg < 4; reg++)
                    out[(size_t)(rbase + reg) * N + col] = v[reg];
            }
        }
    }
}

// ---------- per-layer weight prep: all 6 transposes + bias concat in ONE dispatch ----------
__global__ __launch_bounds__(256)
void prep_layer(const float* __restrict__ Wq, const float* __restrict__ Wk,
                const float* __restrict__ Wv, const float* __restrict__ Wo,
                const float* __restrict__ Wi, const float* __restrict__ Wo2,
                const float* __restrict__ bq, const float* __restrict__ bk,
                const float* __restrict__ bv,
                u16* __restrict__ WtQKV, u16* __restrict__ WtO,
                u16* __restrict__ WtI, u16* __restrict__ WtO2,
                float* __restrict__ bqkv)
{
    const int id  = blockIdx.x;
    const int tid = threadIdx.x;
    if (id == 6912) {                      // bias concat (q scaled by 1/8)
        for (int i = tid; i < QKVW; i += 256) {
            if (i < 768)       bqkv[i] = bq[i] * 0.125f;
            else if (i < 1536) bqkv[i] = bk[i - 768];
            else               bqkv[i] = bv[i - 1536];
        }
        return;
    }
    const float* src; u16* dst; int K, N, t; float scale = 1.f;
    if (id < 2304) {
        const int m = id / 576; t = id % 576; K = 768; N = 768;
        if      (m == 0) { src = Wq; dst = WtQKV;             scale = 0.125f; }
        else if (m == 1) { src = Wk; dst = WtQKV + 768*768; }
        else if (m == 2) { src = Wv; dst = WtQKV + 2*768*768; }
        else             { src = Wo; dst = WtO; }
    } else if (id < 4608) { t = id - 2304; K = 768;  N = 3072; src = Wi;  dst = WtI;  }
    else                  { t = id - 4608; K = 3072; N = 768;  src = Wo2; dst = WtO2; }

    const int ntx = N / 32;
    const int bx = (t / ntx) * 32, by = (t % ntx) * 32;
    __shared__ float tt[32][33];
    const int tx = tid & 31, ty = tid >> 5;
    for (int i = 0; i < 4; i++)
        tt[ty + i*8][tx] = src[(size_t)(bx + ty + i*8) * N + by + tx];
    __syncthreads();
    for (int i = 0; i < 4; i++)
        dst[(size_t)(by + ty + i*8) * K + bx + tx] = f2bf(tt[tx][ty + i*8] * scale);
}

// ---------- embedding ----------
__global__ void embed_kernel(const int* __restrict__ ids, const float* __restrict__ we,
                             const float* __restrict__ pe, const float* __restrict__ te,
                             u16* __restrict__ pb)
{
    const int t = blockIdx.x;
    const int s = t & (SEQ - 1);
    const int id = ids[t];
    const size_t wb = (size_t)id * HID;
    const size_t pbase = (size_t)(s + 2) * HID;
    for (int d = threadIdx.x; d < HID; d += 256)
        pb[(size_t)t * HID + d] = f2bf(we[wb + d] + pe[pbase + d] + te[d]);
}

// ---------- fused layernorm (bf16 pre): x = resid(f32, may be null) + pre ----------
__global__ __launch_bounds__(256)
void ln_kernel(const u16* __restrict__ pre, const float* __restrict__ resid,
               const float* __restrict__ g, const float* __restrict__ bta,
               float* __restrict__ h, u16* __restrict__ hb)
{
    const int t = blockIdx.x;
    float v[3], s = 0.f, s2 = 0.f;
    for (int i = 0; i < 3; i++) {
        const int d = threadIdx.x + i*256;
        float x = bf2f(pre[(size_t)t*HID + d]);
        if (resid) x += resid[(size_t)t*HID + d];
        v[i] = x; s += x; s2 += x*x;
    }
    for (int o = 32; o > 0; o >>= 1) { s += __shfl_xor(s, o, 64); s2 += __shfl_xor(s2, o, 64); }
    __shared__ float red[8];
    const int w = threadIdx.x >> 6, lane = threadIdx.x & 63;
    if (lane == 0) { red[w] = s; red[w+4] = s2; }
    __syncthreads();
    s  = red[0] + red[1] + red[2] + red[3];
    s2 = red[4] + red[5] + red[6] + red[7];
    const float mean = s * (1.f/768.f);
    const float var  = s2 * (1.f/768.f) - mean*mean;
    const float rs   = rsqrtf(fmaxf(var, 0.f) + 1e-5f);
    for (int i = 0; i < 3; i++) {
        const int d = threadIdx.x + i*256;
        const float y = (v[i] - mean) * rs * g[d] + bta[d];
        h [(size_t)t*HID + d] = y;
        hb[(size_t)t*HID + d] = f2bf(y);
    }
}

// ---------- fused layernorm (two f32 split-K partials): x = p0 + p1 + bias + resid ----------
__global__ __launch_bounds__(256)
void ln_kernel_f32(const float* __restrict__ p0, const float* __restrict__ p1,
                   const float* __restrict__ bias, const float* __restrict__ resid,
                   const float* __restrict__ g, const float* __restrict__ bta,
                   float* __restrict__ h, u16* __restrict__ hb)
{
    const int t = blockIdx.x;
    float v[3], s = 0.f, s2 = 0.f;
    for (int i = 0; i < 3; i++) {
        const int d = threadIdx.x + i*256;
        const size_t ix = (size_t)t*HID + d;
        float x = p0[ix] + p1[ix] + bias[d] + resid[ix];
        v[i] = x; s += x; s2 += x*x;
    }
    for (int o = 32; o > 0; o >>= 1) { s += __shfl_xor(s, o, 64); s2 += __shfl_xor(s2, o, 64); }
    __shared__ float red[8];
    const int w = threadIdx.x >> 6, lane = threadIdx.x & 63;
    if (lane == 0) { red[w] = s; red[w+4] = s2; }
    __syncthreads();
    s  = red[0] + red[1] + red[2] + red[3];
    s2 = red[4] + red[5] + red[6] + red[7];
    const float mean = s * (1.f/768.f);
    const float var  = s2 * (1.f/768.f) - mean*mean;
    const float rs   = rsqrtf(fmaxf(var, 0.f) + 1e-5f);
    for (int i = 0; i < 3; i++) {
        const int d = threadIdx.x + i*256;
        const float y = (v[i] - mean) * rs * g[d] + bta[d];
        h [(size_t)t*HID + d] = y;
        hb[(size_t)t*HID + d] = f2bf(y);
    }
}

// ---------- sliding-window attention ----------
__global__ __launch_bounds__(256)
void attn_kernel(const u16* __restrict__ qkv, const int* __restrict__ amask,
                 u16* __restrict__ aout)
{
    const int bid = blockIdx.x;
    const int c  = bid & 15;
    const int hh = (bid >> 4) % 12;
    const int b  = bid / 192;
    const int tid = threadIdx.x;
    const int w = tid >> 6, lane = tid & 63;
    const int quad = lane >> 4, l16 = lane & 15;

    __shared__ __align__(16) u16 Vt[64 * 72];
    __shared__ __align__(16) u16 P[4 * 64 * 72];
    __shared__ int kmS[64];

    const u16* qbase = qkv + (size_t)(b * SEQ) * QKVW + hh * 64;

    short8 qa[4][2];
    const int qrow_base = c * 256 + w * 64;
    for (int mt = 0; mt < 4; mt++)
        for (int ks = 0; ks < 2; ks++) {
            const int t_q = qrow_base + mt*16 + l16;
            qa[mt][ks] = *(const short8*)(qbase + (size_t)t_q * QKVW + ks*32 + quad*8);
        }

    f32x4 oacc[4][5];
    for (int i = 0; i < 4; i++) for (int j = 0; j < 5; j++)
        oacc[i][j] = (f32x4){0.f, 0.f, 0.f, 0.f};
    short8 ones8;
    for (int j = 0; j < 8; j++) ones8[j] = 0x3F80;

    const int kglob0 = (c - 1) * 256;
    u16* Pw = P + w * (64 * 72);

    for (int ch = 0; ch < 12; ch++) {
        __syncthreads();
        {
            const int kl = tid & 63;
            const int dpart = tid >> 6;
            const int gk = kglob0 + ch*64 + kl;
            const bool gok = (gk >= 0 && gk < SEQ);
            for (int i = 0; i < 2; i++) {
                const int d0 = dpart*16 + i*8;
                short8 vv = {0,0,0,0,0,0,0,0};
                if (gok) vv = *(const short8*)(qkv + (size_t)(b*SEQ + gk)*QKVW + 1536 + hh*64 + d0);
                for (int j = 0; j < 8; j++) Vt[(d0 + j)*72 + kl] = (u16)vv[j];
            }
            if (tid < 64) kmS[kl] = gok ? amask[b*SEQ + gk] : 0;
        }
        __syncthreads();

        for (int nt = 0; nt < 4; nt++) {
            short8 kb0 = {0,0,0,0,0,0,0,0}, kb1 = {0,0,0,0,0,0,0,0};
            const int gk = kglob0 + ch*64 + nt*16 + l16;
            if (gk >= 0 && gk < SEQ) {
                const u16* kp = qkv + (size_t)(b*SEQ + gk)*QKVW + 768 + hh*64;
                kb0 = *(const short8*)(kp + quad*8);
                kb1 = *(const short8*)(kp + 32 + quad*8);
            }
            f32x4 sacc[4];
            for (int mt = 0; mt < 4; mt++) {
                sacc[mt] = (f32x4){0.f, 0.f, 0.f, 0.f};
                sacc[mt] = MFMA(qa[mt][0], kb0, sacc[mt]);
                sacc[mt] = MFMA(qa[mt][1], kb1, sacc[mt]);
            }
            const int tband = ch*64 + nt*16 + l16;
            const int km = kmS[nt*16 + l16];
            for (int mt = 0; mt < 4; mt++)
                for (int reg = 0; reg < 4; reg++) {
                    const int rloc = mt*16 + quad*4 + reg;
                    const int rq = w*64 + rloc;
                    const int dt = tband - rq;
                    float p = 0.f;
                    if (dt >= 0 && dt <= 512 && km) p = __expf(fminf(sacc[mt][reg], 30.f));
                    Pw[rloc*72 + nt*16 + l16] = f2bf(p);
                }
        }

        for (int ks = 0; ks < 2; ks++) {
            short8 vb[4];
            for (int nd = 0; nd < 4; nd++)
                vb[nd] = *(const short8*)&Vt[(nd*16 + l16)*72 + ks*32 + quad*8];
            for (int mt = 0; mt < 4; mt++) {
                short8 pa = *(const short8*)&Pw[(mt*16 + l16)*72 + ks*32 + quad*8];
                for (int nd = 0; nd < 4; nd++)
                    oacc[mt][nd] = MFMA(pa, vb[nd], oacc[mt][nd]);
                oacc[mt][4] = MFMA(pa, ones8, oacc[mt][4]);
            }
        }
    }

    u16* obase = aout + (size_t)(b * SEQ) * HID + hh * 64;
    for (int mt = 0; mt < 4; mt++)
        for (int reg = 0; reg < 4; reg++) {
            const int t_q = qrow_base + mt*16 + quad*4 + reg;
            const float l = oacc[mt][4][reg];
            const float rl = (l > 1e-30f) ? 1.f / l : 0.f;
            for (int nd = 0; nd < 4; nd++)
                obase[(size_t)t_q * HID + nd*16 + l16] = f2bf(oacc[mt][nd][reg] * rl);
        }
}

// ---------- classifier ----------
__global__ void cls1(const float* __restrict__ h, const float* __restrict__ w1,
                     const float* __restrict__ b1, float* __restrict__ x)
{
    const int j = blockIdx.x, b = blockIdx.y;
    const float* p = h + (size_t)(b * SEQ) * HID;
    float s = 0.f;
    for (int d = threadIdx.x; d < HID; d += 64) s += p[d] * w1[(size_t)d*512 + j];
    for (int o = 32; o > 0; o >>= 1) s += __shfl_xor(s, o, 64);
    if (threadIdx.x == 0) x[b*512 + j] = fmaxf(s + b1[j], 0.f);
}

__global__ void cls2(const float* __restrict__ x, const float* __restrict__ w2,
                     const float* __restrict__ b2, float* __restrict__ out)
{
    const int j = blockIdx.x, b = blockIdx.y;
    float s = 0.f;
    for (int d = threadIdx.x; d < 512; d += 64) s += x[b*512 + d] * w2[(size_t)d*43 + j];
    for (int o = 32; o > 0; o >>= 1) s += __shfl_xor(s, o, 64);
    if (threadIdx.x == 0) out[b*43 + j] = s + b2[j];
}

// ---------- host ----------
extern "C" void kernel_launch(void* const* d_in, const int* in_sizes, int n_in,
                              void* d_out, int out_size, void* d_ws, size_t ws_size,
                              hipStream_t stream)
{
    const int*   ids   = (const int*)d_in[0];
    const int*   amask = (const int*)d_in[1];
    const float* we  = (const float*)d_in[2];
    const float* pe  = (const float*)d_in[3];
    const float* te  = (const float*)d_in[4];
    const float* eg  = (const float*)d_in[5];
    const float* ebp = (const float*)d_in[6];
    const float* Wq_  = (const float*)d_in[7];
    const float* bq_  = (const float*)d_in[8];
    const float* Wk_  = (const float*)d_in[9];
    const float* bk_  = (const float*)d_in[10];
    const float* Wv_  = (const float*)d_in[11];
    const float* bv_  = (const float*)d_in[12];
    const float* Wo_  = (const float*)d_in[13];
    const float* bo_  = (const float*)d_in[14];
    const float* g1_  = (const float*)d_in[15];
    const float* b1_  = (const float*)d_in[16];
    const float* Wi_  = (const float*)d_in[17];
    const float* bi_  = (const float*)d_in[18];
    const float* Wo2_ = (const float*)d_in[19];
    const float* bo2_ = (const float*)d_in[20];
    const float* g2_  = (const float*)d_in[21];
    const float* b2_  = (const float*)d_in[22];
    const float* cw1  = (const float*)d_in[23];
    const float* cb1  = (const float*)d_in[24];
    const float* cw2  = (const float*)d_in[25];
    const float* cb2  = (const float*)d_in[26];

    char* wsb = (char*)d_ws;
    size_t off = 0;
    auto alloc = [&](size_t bytes) -> void* {
        void* p = wsb + off; off += (bytes + 255) & ~(size_t)255; return p;
    };
    const size_t MN = (size_t)8192 * 768;
    float* h    = (float*)alloc(MN*4);                        // residual (f32)
    u16*   hb   = (u16*)  alloc(MN*2);                        // residual (bf16)
    u16*   pb   = (u16*)  alloc(MN*2);                        // pre-LN scratch (bf16)
    float* pf   = (float*)alloc(MN*4*2);                      // 2x f32 split-K partials
    u16*   U    = (u16*)  alloc((size_t)8192*3072*2);         // qkv|ao union == fbuf
    u16*   qkv  = U;
    u16*   ao   = U + (size_t)8192*QKVW;
    u16*   fbuf = U;
    u16*   WtQKV= (u16*)  alloc((size_t)QKVW*768*2);
    float* bqkv = (float*)alloc((size_t)QKVW*4);
    u16*   WtO  = (u16*)  alloc((size_t)768*768*2);
    u16*   WtI  = (u16*)  alloc((size_t)3072*768*2);
    u16*   WtO2 = (u16*)  alloc((size_t)768*3072*2);
    float* clsx = (float*)alloc((size_t)2*512*4);

    embed_kernel<<<8192, 256, 0, stream>>>(ids, we, pe, te, pb);
    ln_kernel<<<8192, 256, 0, stream>>>(pb, nullptr, eg, ebp, h, hb);

    for (int l = 0; l < 12; l++) {
        const size_t wHH = (size_t)l * 768 * 768;
        const size_t wHF = (size_t)l * 768 * 3072;
        prep_layer<<<6913, 256, 0, stream>>>(Wq_ + wHH, Wk_ + wHH, Wv_ + wHH, Wo_ + wHH,
                                             Wi_ + wHF, Wo2_ + wHF,
                                             bq_ + l*768, bk_ + l*768, bv_ + l*768,
                                             WtQKV, WtO, WtI, WtO2, bqkv);

        // fused QKV projection (q pre-scaled by 1/8)
        gemm_bt<0,0><<<dim3(64,18,1), 256, 0, stream>>>(hb, WtQKV, bqkv, qkv, 8192, QKVW, 768, 768);
        // sliding-window attention
        attn_kernel<<<384, 256, 0, stream>>>(qkv, amask, ao);
        // output projection: split-K=2 into f32 partial buffers; bias folded into LN1
        gemm_bt<1,0><<<dim3(64,6,2), 256, 0, stream>>>(ao, WtO, nullptr, pf, 8192, 768, 768, 384);
        ln_kernel_f32<<<8192, 256, 0, stream>>>(pf, pf + MN, bo_ + l*768, h,
                                                g1_ + l*768, b1_ + l*768, h, hb);
        // FFN
        gemm_bt<0,1><<<dim3(64,24,1), 256, 0, stream>>>(hb, WtI, bi_ + l*3072, fbuf, 8192, 3072, 768, 768);
        // FFN2: split-K=2 into f32 partial buffers; bias folded into LN2
        gemm_bt<1,0><<<dim3(64,6,2), 256, 0, stream>>>(fbuf, WtO2, nullptr, pf, 8192, 768, 3072, 1536);
        ln_kernel_f32<<<8192, 256, 0, stream>>>(pf, pf + MN, bo2_ + l*768, h,
                                                g2_ + l*768, b2_ + l*768, h, hb);
    }

    cls1<<<dim3(512,2), 64, 0, stream>>>(h, cw1, cb1, clsx);
    cls2<<<dim3(43,2),  64, 0, stream>>>(clsx, cw2, cb2, (float*)d_out);
}